// Round 5
// baseline (362.335 us; speedup 1.0000x reference)
//
#include <hip/hip_runtime.h>
#include <float.h>

// B=4, S=2048, D=1024, H=16, hd=64. bf16 MFMA pipeline:
//   cast_x, transpose_cast(w_qkv), transpose_cast(w_out)
//   gemm_qkv (MFMA 128x128) -> qN (pre-scaled by 1/8*log2e), kN [bh][S][64], vT [bh][64][S]
//   attn (MFMA flash, barrier-free K-loop: K/V global->VGPR, wave-autonomous)
//   gemm_out (MFMA 128x128) -> out fp32

#define SEQ   2048
#define DIM   1024
#define NH    16
#define HD    64
#define MROWS 8192
#define BHTOT 64
#define QTILE 128
#define PSTR  72          // PT row stride in bf16 (144 B = 36 dwords; conflict-free)

typedef __bf16 bf16_t;
typedef __bf16 bf16x4 __attribute__((ext_vector_type(4)));
typedef __bf16 bf16x8 __attribute__((ext_vector_type(8)));
typedef float  f32x4  __attribute__((ext_vector_type(4)));

typedef const __attribute__((address_space(1))) unsigned int* gas_ptr;
typedef __attribute__((address_space(3))) unsigned int* las_ptr;

__device__ __forceinline__ void gll16(const bf16_t* g, bf16_t* l) {
    __builtin_amdgcn_global_load_lds((gas_ptr)g, (las_ptr)l, 16, 0, 0);
}

// ---------------- cast kernels ----------------
__global__ __launch_bounds__(256) void cast_x_kernel(
    const float* __restrict__ x, bf16_t* __restrict__ xb)
{
    int i = (blockIdx.x * 256 + threadIdx.x) * 4;
    float4 v = *(const float4*)(x + i);
    bf16x4 o = { (bf16_t)v.x, (bf16_t)v.y, (bf16_t)v.z, (bf16_t)v.w };
    *(bf16x4*)(xb + i) = o;
}

// w [K][N] fp32 -> wT [N][K] bf16
__global__ __launch_bounds__(256) void transpose_cast_kernel(
    const float* __restrict__ w, bf16_t* __restrict__ wT, int K, int N)
{
    __shared__ float t[32][33];
    const int bk = blockIdx.x * 32, bn = blockIdx.y * 32;
    const int r = threadIdx.x >> 5, c = threadIdx.x & 31;
    #pragma unroll
    for (int i = 0; i < 4; i++)
        t[r + i * 8][c] = w[(size_t)(bk + r + i * 8) * N + bn + c];
    __syncthreads();
    #pragma unroll
    for (int i = 0; i < 4; i++)
        wT[(size_t)(bn + r + i * 8) * K + bk + c] = (bf16_t)t[c][r + i * 8];
}

// ---------------- GEMM qkv: 128x128 tile, BK=64, XOR-granule swizzle ----------------
__global__ __launch_bounds__(256) void gemm_qkv_kernel(
    const bf16_t* __restrict__ A,    // [8192][1024]
    const bf16_t* __restrict__ Bt,   // [3072][1024]
    bf16_t* __restrict__ qN, bf16_t* __restrict__ kN, bf16_t* __restrict__ vT)
{
    __shared__ bf16_t As[128 * 64];
    __shared__ bf16_t Bs[128 * 64];
    const int tid = threadIdx.x;
    const int lane = tid & 63, w = tid >> 6;
    const int quad = lane >> 4, l16 = lane & 15;
    const int wr = w >> 1, wc = w & 1;
    const int bm = blockIdx.x * 128, bn = blockIdx.y * 128;

    f32x4 acc[4][4] = {};

    for (int k0 = 0; k0 < DIM; k0 += 64) {
        __syncthreads();
        #pragma unroll
        for (int p = 0; p < 4; p++) {
            int flat = p * 256 + tid;
            int row = flat >> 3, g = flat & 7;
            int gs = g ^ (row & 7);
            gll16(A  + (size_t)(bm + row) * DIM + k0 + gs * 8, As + (size_t)(p * 256 + w * 64) * 8);
            gll16(Bt + (size_t)(bn + row) * DIM + k0 + gs * 8, Bs + (size_t)(p * 256 + w * 64) * 8);
        }
        __syncthreads();
        #pragma unroll
        for (int ks = 0; ks < 2; ks++) {
            bf16x8 af[4], bfv[4];
            #pragma unroll
            for (int mt = 0; mt < 4; mt++) {
                int row = wr * 64 + mt * 16 + l16;
                int g = (ks * 4 + quad) ^ (row & 7);
                af[mt] = *(const bf16x8*)(As + row * 64 + g * 8);
            }
            #pragma unroll
            for (int nt = 0; nt < 4; nt++) {
                int row = wc * 64 + nt * 16 + l16;
                int g = (ks * 4 + quad) ^ (row & 7);
                bfv[nt] = *(const bf16x8*)(Bs + row * 64 + g * 8);
            }
            #pragma unroll
            for (int mt = 0; mt < 4; mt++)
                #pragma unroll
                for (int nt = 0; nt < 4; nt++)
                    acc[mt][nt] = __builtin_amdgcn_mfma_f32_16x16x32_bf16(
                        af[mt], bfv[nt], acc[mt][nt], 0, 0, 0);
        }
    }

    const int which = bn >> 10;   // 0=q, 1=k, 2=v (uniform per block)
    if (which == 2) {
        #pragma unroll
        for (int mt = 0; mt < 4; mt++)
            #pragma unroll
            for (int nt = 0; nt < 4; nt++) {
                int row0 = bm + wr * 64 + mt * 16 + quad * 4;
                int b = row0 >> 11, s0 = row0 & 2047;
                int col = bn + wc * 64 + nt * 16 + l16;
                int nn = col & 1023, h = nn >> 6, d = nn & 63;
                int bh = b * NH + h;
                bf16x4 vv;
                #pragma unroll
                for (int r = 0; r < 4; r++) vv[r] = (bf16_t)acc[mt][nt][r];
                *(bf16x4*)(vT + ((size_t)bh * HD + d) * SEQ + s0) = vv;
            }
    } else {
        const float qsc = (which == 0) ? 0.18033688011112042f : 1.0f; // (1/8)*log2(e)
        bf16_t* dst = (which == 0) ? qN : kN;
        #pragma unroll
        for (int mt = 0; mt < 4; mt++)
            #pragma unroll
            for (int nt = 0; nt < 4; nt++)
                #pragma unroll
                for (int r = 0; r < 4; r++) {
                    int row = bm + wr * 64 + mt * 16 + quad * 4 + r;
                    int b = row >> 11, s = row & 2047;
                    int col = bn + wc * 64 + nt * 16 + l16;
                    int nn = col & 1023, h = nn >> 6, d = nn & 63;
                    int bh = b * NH + h;
                    dst[((size_t)bh * SEQ + s) * HD + d] = (bf16_t)(acc[mt][nt][r] * qsc);
                }
    }
}

__global__ __launch_bounds__(256) void gemm_out_kernel(
    const bf16_t* __restrict__ A,    // attnb [8192][1024]
    const bf16_t* __restrict__ Bt,   // woutT [1024][1024]
    float* __restrict__ out)
{
    __shared__ bf16_t As[128 * 64];
    __shared__ bf16_t Bs[128 * 64];
    const int tid = threadIdx.x;
    const int lane = tid & 63, w = tid >> 6;
    const int quad = lane >> 4, l16 = lane & 15;
    const int wr = w >> 1, wc = w & 1;
    const int bm = blockIdx.x * 128, bn = blockIdx.y * 128;

    f32x4 acc[4][4] = {};

    for (int k0 = 0; k0 < DIM; k0 += 64) {
        __syncthreads();
        #pragma unroll
        for (int p = 0; p < 4; p++) {
            int flat = p * 256 + tid;
            int row = flat >> 3, g = flat & 7;
            int gs = g ^ (row & 7);
            gll16(A  + (size_t)(bm + row) * DIM + k0 + gs * 8, As + (size_t)(p * 256 + w * 64) * 8);
            gll16(Bt + (size_t)(bn + row) * DIM + k0 + gs * 8, Bs + (size_t)(p * 256 + w * 64) * 8);
        }
        __syncthreads();
        #pragma unroll
        for (int ks = 0; ks < 2; ks++) {
            bf16x8 af[4], bfv[4];
            #pragma unroll
            for (int mt = 0; mt < 4; mt++) {
                int row = wr * 64 + mt * 16 + l16;
                int g = (ks * 4 + quad) ^ (row & 7);
                af[mt] = *(const bf16x8*)(As + row * 64 + g * 8);
            }
            #pragma unroll
            for (int nt = 0; nt < 4; nt++) {
                int row = wc * 64 + nt * 16 + l16;
                int g = (ks * 4 + quad) ^ (row & 7);
                bfv[nt] = *(const bf16x8*)(Bs + row * 64 + g * 8);
            }
            #pragma unroll
            for (int mt = 0; mt < 4; mt++)
                #pragma unroll
                for (int nt = 0; nt < 4; nt++)
                    acc[mt][nt] = __builtin_amdgcn_mfma_f32_16x16x32_bf16(
                        af[mt], bfv[nt], acc[mt][nt], 0, 0, 0);
        }
    }

    #pragma unroll
    for (int mt = 0; mt < 4; mt++)
        #pragma unroll
        for (int nt = 0; nt < 4; nt++)
            #pragma unroll
            for (int r = 0; r < 4; r++) {
                int row = bm + wr * 64 + mt * 16 + quad * 4 + r;
                int col = bn + wc * 64 + nt * 16 + l16;
                out[(size_t)row * DIM + col] = acc[mt][nt][r];
            }
}

// ---------------- MFMA flash attention, barrier-free K-loop ----------------
// grid (BHTOT, SEQ/QTILE), y->qb via magic square (per-CU balance).
// Wave w owns q-rows [w*32, w*32+32). K/V fragments loaded global->VGPR
// (no LDS staging, NO __syncthreads in the loop). S^T = K·Q^T, P^T via
// stride-72 LDS (conflict-free b64 writes / b128 reads), O^T = V^T·P^T.
__device__ __constant__ int QB_TAB[16] = {0,11,7,12, 14,5,9,2, 13,6,10,1, 3,8,4,15};

__global__ __launch_bounds__(256) void attn_kernel(
    const bf16_t* __restrict__ qN, const bf16_t* __restrict__ kN,
    const bf16_t* __restrict__ vT, bf16_t* __restrict__ attnb)
{
    __shared__ __align__(16) char smem[QTILE * PSTR * 2];   // 18.4 KB: Q tile then PT
    bf16_t* QPs = (bf16_t*)smem;

    const int bh = blockIdx.x;
    const int qb = QB_TAB[blockIdx.y];
    const int tid = threadIdx.x;
    const int lane = tid & 63, w = tid >> 6;
    const int quad = lane >> 4, l16 = lane & 15;

    const bf16_t* qbase = qN + (size_t)bh * SEQ * HD;
    const bf16_t* kbase = kN + (size_t)bh * SEQ * HD;
    const bf16_t* vbase = vT + (size_t)bh * HD * SEQ;

    // stage Q tile (128x64, XOR-granule swizzle) -> fragments -> regs
    #pragma unroll
    for (int p = 0; p < 4; p++) {
        int flat = p * 256 + tid;
        int row = flat >> 3, g = flat & 7;
        int gs = g ^ (row & 7);
        gll16(qbase + (size_t)(qb * QTILE + row) * HD + gs * 8,
              QPs + (size_t)(p * 256 + w * 64) * 8);
    }
    __syncthreads();

    bf16x8 qa[2][2];   // B-operand fragments: n = qrow
    #pragma unroll
    for (int mt = 0; mt < 2; mt++)
        #pragma unroll
        for (int ks = 0; ks < 2; ks++) {
            int row = w * 32 + mt * 16 + l16;
            int g = (ks * 4 + quad) ^ (row & 7);
            qa[mt][ks] = *(const bf16x8*)(QPs + row * 64 + g * 8);
        }
    __syncthreads();   // all Q-frag reads done before PT overwrites (PT rows alias other waves' Q)

    f32x4 o[4][2] = {};        // O^T: rows d = dt*16+quad*4+r, col qrow = l16 (mt block)
    float l_part[2] = {};

    // per-wave iteration bound (waves 0,1: 2qb+1 iters; waves 2,3: 2qb+2)
    const int wave_row_max = qb * QTILE + w * 32 + 31;
    const int ktend = min(2 * qb + 1, wave_row_max >> 6);

    for (int kt = 0; kt <= ktend; kt++) {
        // ---- K fragments: global -> VGPR (A-operand for S^T = K·Q^T) ----
        bf16x8 kb[2][4];
        #pragma unroll
        for (int ks = 0; ks < 2; ks++)
            #pragma unroll
            for (int nt = 0; nt < 4; nt++)
                kb[ks][nt] = *(const bf16x8*)(
                    kbase + (size_t)(kt * 64 + nt * 16 + l16) * HD + ks * 32 + quad * 8);

        // ---- S^T = K Q^T : s[nt][mt], key = kt*64+nt*16+quad*4+r, qrow col = l16 ----
        f32x4 s[4][2] = {};
        #pragma unroll
        for (int ks = 0; ks < 2; ks++)
            #pragma unroll
            for (int nt = 0; nt < 4; nt++)
                #pragma unroll
                for (int mt = 0; mt < 2; mt++)
                    s[nt][mt] = __builtin_amdgcn_mfma_f32_16x16x32_bf16(
                        kb[ks][nt], qa[mt][ks], s[nt][mt], 0, 0, 0);

        // ---- p = exp2(s) (Q pre-scaled), accumulate l, packed P^T store ----
        const bool maskit = (kt >= 2 * qb);
        #pragma unroll
        for (int mt = 0; mt < 2; mt++) {
            const int rl = w * 32 + mt * 16 + l16;          // qrow local
            const int qrow = qb * QTILE + rl;
            #pragma unroll
            for (int nt = 0; nt < 4; nt++) {
                bf16x4 pk;
                #pragma unroll
                for (int r = 0; r < 4; r++) {
                    float pv;
                    if (maskit) {
                        int key = kt * 64 + nt * 16 + quad * 4 + r;
                        pv = (key <= qrow) ? __builtin_amdgcn_exp2f(s[nt][mt][r]) : 0.0f;
                    } else {
                        pv = __builtin_amdgcn_exp2f(s[nt][mt][r]);
                    }
                    l_part[mt] += pv;
                    pk[r] = (bf16_t)pv;
                }
                *(bf16x4*)(QPs + rl * PSTR + nt * 16 + quad * 4) = pk;   // PT[qrow][key]
            }
        }

        // ---- O^T += V^T P^T (V fragments global -> VGPR) ----
        #pragma unroll
        for (int ks = 0; ks < 2; ks++) {
            bf16x8 vb[4], pb[2];
            #pragma unroll
            for (int dt = 0; dt < 4; dt++)
                vb[dt] = *(const bf16x8*)(
                    vbase + (size_t)(dt * 16 + l16) * SEQ + kt * 64 + ks * 32 + quad * 8);
            #pragma unroll
            for (int mt = 0; mt < 2; mt++) {
                int rl = w * 32 + mt * 16 + l16;
                pb[mt] = *(const bf16x8*)(QPs + rl * PSTR + ks * 32 + quad * 8);
            }
            #pragma unroll
            for (int dt = 0; dt < 4; dt++)
                #pragma unroll
                for (int mt = 0; mt < 2; mt++)
                    o[dt][mt] = __builtin_amdgcn_mfma_f32_16x16x32_bf16(
                        vb[dt], pb[mt], o[dt][mt], 0, 0, 0);
        }
    }

    // ---- epilogue: reduce l across quads (lanes l16, +16, +32, +48 share qrow) ----
    const int b = bh >> 4, h = bh & 15;
    #pragma unroll
    for (int mt = 0; mt < 2; mt++) {
        float lsum = l_part[mt];
        lsum += __shfl_xor(lsum, 16, 64);
        lsum += __shfl_xor(lsum, 32, 64);
        float inv = 1.0f / lsum;
        int srow = qb * QTILE + w * 32 + mt * 16 + l16;
        #pragma unroll
        for (int dt = 0; dt < 4; dt++) {
            bf16x4 ov;
            #pragma unroll
            for (int r = 0; r < 4; r++) ov[r] = (bf16_t)(o[dt][mt][r] * inv);
            *(bf16x4*)(attnb + ((size_t)(b * SEQ + srow)) * DIM + h * HD + dt * 16 + quad * 4) = ov;
        }
    }
}

extern "C" void kernel_launch(void* const* d_in, const int* in_sizes, int n_in,
                              void* d_out, int out_size, void* d_ws, size_t ws_size,
                              hipStream_t stream) {
    const float* x     = (const float*)d_in[0];
    const float* w_qkv = (const float*)d_in[1];
    const float* w_out = (const float*)d_in[2];
    float* out = (float*)d_out;

    bf16_t* xb    = (bf16_t*)d_ws;                          // 8192*1024
    bf16_t* wqkvT = xb    + (size_t)MROWS * DIM;            // 3072*1024
    bf16_t* woutT = wqkvT + (size_t)3 * DIM * DIM;          // 1024*1024
    bf16_t* qNb   = woutT + (size_t)DIM * DIM;              // 64*2048*64
    bf16_t* kNb   = qNb   + (size_t)BHTOT * SEQ * HD;
    bf16_t* vTb   = kNb   + (size_t)BHTOT * SEQ * HD;
    bf16_t* attnb = vTb   + (size_t)BHTOT * SEQ * HD;       // 8192*1024

    cast_x_kernel<<<MROWS * DIM / 1024, 256, 0, stream>>>(x, xb);
    transpose_cast_kernel<<<dim3(DIM / 32, 3 * DIM / 32), 256, 0, stream>>>(w_qkv, wqkvT, DIM, 3 * DIM);
    transpose_cast_kernel<<<dim3(DIM / 32, DIM / 32), 256, 0, stream>>>(w_out, woutT, DIM, DIM);
    gemm_qkv_kernel<<<dim3(MROWS / 128, 3 * DIM / 128), 256, 0, stream>>>(xb, wqkvT, qNb, kNb, vTb);
    attn_kernel<<<dim3(BHTOT, SEQ / QTILE), 256, 0, stream>>>(qNb, kNb, vTb, attnb);
    gemm_out_kernel<<<dim3(MROWS / 128, DIM / 128), 256, 0, stream>>>(attnb, woutT, out);
}

// Round 6
// 344.367 us; speedup vs baseline: 1.0522x; 1.0522x over previous
//
#include <hip/hip_runtime.h>
#include <float.h>

// B=4, S=2048, D=1024, H=16, hd=64. bf16 MFMA pipeline:
//   cast_x, transpose_cast(w_qkv), transpose_cast(w_out)
//   gemm_qkv (MFMA 128x128) -> qN (pre-scaled by 1/8*log2e), kN [bh][S][64], vT [bh][64][S]
//   attn (MFMA flash, barrier-free K-loop, register-pipelined K/V, swizzled P^T)
//   gemm_out (MFMA 128x128) -> out fp32

#define SEQ   2048
#define DIM   1024
#define NH    16
#define HD    64
#define MROWS 8192
#define BHTOT 64
#define QTILE 128

typedef __bf16 bf16_t;
typedef __bf16 bf16x4 __attribute__((ext_vector_type(4)));
typedef __bf16 bf16x8 __attribute__((ext_vector_type(8)));
typedef float  f32x4  __attribute__((ext_vector_type(4)));

typedef const __attribute__((address_space(1))) unsigned int* gas_ptr;
typedef __attribute__((address_space(3))) unsigned int* las_ptr;

__device__ __forceinline__ void gll16(const bf16_t* g, bf16_t* l) {
    __builtin_amdgcn_global_load_lds((gas_ptr)g, (las_ptr)l, 16, 0, 0);
}

// ---------------- cast kernels ----------------
__global__ __launch_bounds__(256) void cast_x_kernel(
    const float* __restrict__ x, bf16_t* __restrict__ xb)
{
    int i = (blockIdx.x * 256 + threadIdx.x) * 4;
    float4 v = *(const float4*)(x + i);
    bf16x4 o = { (bf16_t)v.x, (bf16_t)v.y, (bf16_t)v.z, (bf16_t)v.w };
    *(bf16x4*)(xb + i) = o;
}

// w [K][N] fp32 -> wT [N][K] bf16
__global__ __launch_bounds__(256) void transpose_cast_kernel(
    const float* __restrict__ w, bf16_t* __restrict__ wT, int K, int N)
{
    __shared__ float t[32][33];
    const int bk = blockIdx.x * 32, bn = blockIdx.y * 32;
    const int r = threadIdx.x >> 5, c = threadIdx.x & 31;
    #pragma unroll
    for (int i = 0; i < 4; i++)
        t[r + i * 8][c] = w[(size_t)(bk + r + i * 8) * N + bn + c];
    __syncthreads();
    #pragma unroll
    for (int i = 0; i < 4; i++)
        wT[(size_t)(bn + r + i * 8) * K + bk + c] = (bf16_t)t[c][r + i * 8];
}

// ---------------- GEMM qkv: 128x128 tile, BK=64, XOR-granule swizzle ----------------
__global__ __launch_bounds__(256) void gemm_qkv_kernel(
    const bf16_t* __restrict__ A,    // [8192][1024]
    const bf16_t* __restrict__ Bt,   // [3072][1024]
    bf16_t* __restrict__ qN, bf16_t* __restrict__ kN, bf16_t* __restrict__ vT)
{
    __shared__ bf16_t As[128 * 64];
    __shared__ bf16_t Bs[128 * 64];
    const int tid = threadIdx.x;
    const int lane = tid & 63, w = tid >> 6;
    const int quad = lane >> 4, l16 = lane & 15;
    const int wr = w >> 1, wc = w & 1;
    const int bm = blockIdx.x * 128, bn = blockIdx.y * 128;

    f32x4 acc[4][4] = {};

    for (int k0 = 0; k0 < DIM; k0 += 64) {
        __syncthreads();
        #pragma unroll
        for (int p = 0; p < 4; p++) {
            int flat = p * 256 + tid;
            int row = flat >> 3, g = flat & 7;
            int gs = g ^ (row & 7);
            gll16(A  + (size_t)(bm + row) * DIM + k0 + gs * 8, As + (size_t)(p * 256 + w * 64) * 8);
            gll16(Bt + (size_t)(bn + row) * DIM + k0 + gs * 8, Bs + (size_t)(p * 256 + w * 64) * 8);
        }
        __syncthreads();
        #pragma unroll
        for (int ks = 0; ks < 2; ks++) {
            bf16x8 af[4], bfv[4];
            #pragma unroll
            for (int mt = 0; mt < 4; mt++) {
                int row = wr * 64 + mt * 16 + l16;
                int g = (ks * 4 + quad) ^ (row & 7);
                af[mt] = *(const bf16x8*)(As + row * 64 + g * 8);
            }
            #pragma unroll
            for (int nt = 0; nt < 4; nt++) {
                int row = wc * 64 + nt * 16 + l16;
                int g = (ks * 4 + quad) ^ (row & 7);
                bfv[nt] = *(const bf16x8*)(Bs + row * 64 + g * 8);
            }
            #pragma unroll
            for (int mt = 0; mt < 4; mt++)
                #pragma unroll
                for (int nt = 0; nt < 4; nt++)
                    acc[mt][nt] = __builtin_amdgcn_mfma_f32_16x16x32_bf16(
                        af[mt], bfv[nt], acc[mt][nt], 0, 0, 0);
        }
    }

    const int which = bn >> 10;   // 0=q, 1=k, 2=v (uniform per block)
    if (which == 2) {
        #pragma unroll
        for (int mt = 0; mt < 4; mt++)
            #pragma unroll
            for (int nt = 0; nt < 4; nt++) {
                int row0 = bm + wr * 64 + mt * 16 + quad * 4;
                int b = row0 >> 11, s0 = row0 & 2047;
                int col = bn + wc * 64 + nt * 16 + l16;
                int nn = col & 1023, h = nn >> 6, d = nn & 63;
                int bh = b * NH + h;
                bf16x4 vv;
                #pragma unroll
                for (int r = 0; r < 4; r++) vv[r] = (bf16_t)acc[mt][nt][r];
                *(bf16x4*)(vT + ((size_t)bh * HD + d) * SEQ + s0) = vv;
            }
    } else {
        const float qsc = (which == 0) ? 0.18033688011112042f : 1.0f; // (1/8)*log2(e)
        bf16_t* dst = (which == 0) ? qN : kN;
        #pragma unroll
        for (int mt = 0; mt < 4; mt++)
            #pragma unroll
            for (int nt = 0; nt < 4; nt++)
                #pragma unroll
                for (int r = 0; r < 4; r++) {
                    int row = bm + wr * 64 + mt * 16 + quad * 4 + r;
                    int b = row >> 11, s = row & 2047;
                    int col = bn + wc * 64 + nt * 16 + l16;
                    int nn = col & 1023, h = nn >> 6, d = nn & 63;
                    int bh = b * NH + h;
                    dst[((size_t)bh * SEQ + s) * HD + d] = (bf16_t)(acc[mt][nt][r] * qsc);
                }
    }
}

__global__ __launch_bounds__(256) void gemm_out_kernel(
    const bf16_t* __restrict__ A,    // attnb [8192][1024]
    const bf16_t* __restrict__ Bt,   // woutT [1024][1024]
    float* __restrict__ out)
{
    __shared__ bf16_t As[128 * 64];
    __shared__ bf16_t Bs[128 * 64];
    const int tid = threadIdx.x;
    const int lane = tid & 63, w = tid >> 6;
    const int quad = lane >> 4, l16 = lane & 15;
    const int wr = w >> 1, wc = w & 1;
    const int bm = blockIdx.x * 128, bn = blockIdx.y * 128;

    f32x4 acc[4][4] = {};

    for (int k0 = 0; k0 < DIM; k0 += 64) {
        __syncthreads();
        #pragma unroll
        for (int p = 0; p < 4; p++) {
            int flat = p * 256 + tid;
            int row = flat >> 3, g = flat & 7;
            int gs = g ^ (row & 7);
            gll16(A  + (size_t)(bm + row) * DIM + k0 + gs * 8, As + (size_t)(p * 256 + w * 64) * 8);
            gll16(Bt + (size_t)(bn + row) * DIM + k0 + gs * 8, Bs + (size_t)(p * 256 + w * 64) * 8);
        }
        __syncthreads();
        #pragma unroll
        for (int ks = 0; ks < 2; ks++) {
            bf16x8 af[4], bfv[4];
            #pragma unroll
            for (int mt = 0; mt < 4; mt++) {
                int row = wr * 64 + mt * 16 + l16;
                int g = (ks * 4 + quad) ^ (row & 7);
                af[mt] = *(const bf16x8*)(As + row * 64 + g * 8);
            }
            #pragma unroll
            for (int nt = 0; nt < 4; nt++) {
                int row = wc * 64 + nt * 16 + l16;
                int g = (ks * 4 + quad) ^ (row & 7);
                bfv[nt] = *(const bf16x8*)(Bs + row * 64 + g * 8);
            }
            #pragma unroll
            for (int mt = 0; mt < 4; mt++)
                #pragma unroll
                for (int nt = 0; nt < 4; nt++)
                    acc[mt][nt] = __builtin_amdgcn_mfma_f32_16x16x32_bf16(
                        af[mt], bfv[nt], acc[mt][nt], 0, 0, 0);
        }
    }

    #pragma unroll
    for (int mt = 0; mt < 4; mt++)
        #pragma unroll
        for (int nt = 0; nt < 4; nt++)
            #pragma unroll
            for (int r = 0; r < 4; r++) {
                int row = bm + wr * 64 + mt * 16 + quad * 4 + r;
                int col = bn + wc * 64 + nt * 16 + l16;
                out[(size_t)row * DIM + col] = acc[mt][nt][r];
            }
}

// ---------------- MFMA flash attention, pipelined barrier-free K-loop ----------------
// grid (BHTOT, SEQ/QTILE), y->qb via magic square (per-CU balance).
// Wave w owns q-rows [w*32, w*32+32). K/V fragments global->VGPR: V issued at
// iter top (covered by S-MFMA+softmax), K for kt+1 double-buffered in regs
// (covered by softmax+PV). NO __syncthreads in the loop. S^T = K·Q^T.
// P^T stored in LDS with the SAME XOR-granule stride-64 swizzle as the Q tile
// (key granule k/8 ^ (row&7), offset k%8): b64 writes / b128 reads uniform.
__device__ __constant__ int QB_TAB[16] = {0,11,7,12, 14,5,9,2, 13,6,10,1, 3,8,4,15};

#define LOADK(dst, kt_) do {                                                        \
    _Pragma("unroll")                                                               \
    for (int ks_ = 0; ks_ < 2; ks_++)                                               \
        _Pragma("unroll")                                                           \
        for (int nt_ = 0; nt_ < 4; nt_++)                                           \
            dst[ks_][nt_] = *(const bf16x8*)(                                       \
                kbase + (size_t)((kt_) * 64 + nt_ * 16 + l16) * HD + ks_ * 32 + quad * 8); \
} while (0)

__global__ __launch_bounds__(256) void attn_kernel(
    const bf16_t* __restrict__ qN, const bf16_t* __restrict__ kN,
    const bf16_t* __restrict__ vT, bf16_t* __restrict__ attnb)
{
    __shared__ __align__(16) bf16_t QPs[QTILE * 64];   // 16 KB: Q tile, then P^T (same swizzle)

    const int bh = blockIdx.x;
    const int qb = QB_TAB[blockIdx.y];
    const int tid = threadIdx.x;
    const int lane = tid & 63, w = tid >> 6;
    const int quad = lane >> 4, l16 = lane & 15;

    const bf16_t* qbase = qN + (size_t)bh * SEQ * HD;
    const bf16_t* kbase = kN + (size_t)bh * SEQ * HD;
    const bf16_t* vbase = vT + (size_t)bh * HD * SEQ;

    // stage Q tile (128x64, XOR-granule swizzle) -> fragments -> regs
    #pragma unroll
    for (int p = 0; p < 4; p++) {
        int flat = p * 256 + tid;
        int row = flat >> 3, g = flat & 7;
        int gs = g ^ (row & 7);
        gll16(qbase + (size_t)(qb * QTILE + row) * HD + gs * 8,
              QPs + (size_t)(p * 256 + w * 64) * 8);
    }
    __syncthreads();

    bf16x8 qa[2][2];   // B-operand fragments: n = qrow (wave-private rows)
    #pragma unroll
    for (int mt = 0; mt < 2; mt++)
        #pragma unroll
        for (int ks = 0; ks < 2; ks++) {
            int row = w * 32 + mt * 16 + l16;
            int g = (ks * 4 + quad) ^ (row & 7);
            qa[mt][ks] = *(const bf16x8*)(QPs + row * 64 + g * 8);
        }
    __syncthreads();   // safety: all Q reads done before P^T overwrites

    f32x4 o[4][2] = {};        // O^T: rows d = dt*16+quad*4+r, col qrow = l16 (mt block)
    float l_part[2] = {};

    // per-wave iteration bound (waves 0,1: 2qb+1 iters; waves 2,3: 2qb+2)
    const int wave_row_max = qb * QTILE + w * 32 + 31;
    const int ktend = min(2 * qb + 1, wave_row_max >> 6);

    bf16x8 kb[2][4];
    LOADK(kb, 0);

    for (int kt = 0; kt <= ktend; kt++) {
        // ---- V fragments for this kt: issue early, consumed at PV ----
        bf16x8 vb[2][4];
        #pragma unroll
        for (int ks = 0; ks < 2; ks++)
            #pragma unroll
            for (int dt = 0; dt < 4; dt++)
                vb[ks][dt] = *(const bf16x8*)(
                    vbase + (size_t)(dt * 16 + l16) * SEQ + kt * 64 + ks * 32 + quad * 8);

        // ---- S^T = K Q^T : s[nt][mt], key = kt*64+nt*16+quad*4+r, qrow col = l16 ----
        f32x4 s[4][2] = {};
        #pragma unroll
        for (int ks = 0; ks < 2; ks++)
            #pragma unroll
            for (int nt = 0; nt < 4; nt++)
                #pragma unroll
                for (int mt = 0; mt < 2; mt++)
                    s[nt][mt] = __builtin_amdgcn_mfma_f32_16x16x32_bf16(
                        kb[ks][nt], qa[mt][ks], s[nt][mt], 0, 0, 0);

        // ---- prefetch K for kt+1 (latency covered by softmax + PV) ----
        bf16x8 kbn[2][4];
        const int ktn = (kt < ktend) ? kt + 1 : kt;   // clamp: stay in bounds
        LOADK(kbn, ktn);

        // ---- p = exp2(s) (Q pre-scaled), accumulate l, swizzled packed P^T store ----
        const bool maskit = (kt >= 2 * qb);
        #pragma unroll
        for (int mt = 0; mt < 2; mt++) {
            const int rl = w * 32 + mt * 16 + l16;          // qrow local
            const int qrow = qb * QTILE + rl;
            #pragma unroll
            for (int nt = 0; nt < 4; nt++) {
                bf16x4 pk;
                #pragma unroll
                for (int r = 0; r < 4; r++) {
                    float pv;
                    if (maskit) {
                        int key = kt * 64 + nt * 16 + quad * 4 + r;
                        pv = (key <= qrow) ? __builtin_amdgcn_exp2f(s[nt][mt][r]) : 0.0f;
                    } else {
                        pv = __builtin_amdgcn_exp2f(s[nt][mt][r]);
                    }
                    l_part[mt] += pv;
                    pk[r] = (bf16_t)pv;
                }
                // key granule = nt*2 + (quad>>1); within-granule offset = (quad&1)*4
                int gw = (nt * 2 + (quad >> 1)) ^ (rl & 7);
                *(bf16x4*)(QPs + rl * 64 + gw * 8 + (quad & 1) * 4) = pk;
            }
        }

        // ---- O^T += V^T P^T ----
        #pragma unroll
        for (int ks = 0; ks < 2; ks++) {
            bf16x8 pb[2];
            #pragma unroll
            for (int mt = 0; mt < 2; mt++) {
                int rl = w * 32 + mt * 16 + l16;
                int gr = (ks * 4 + quad) ^ (rl & 7);
                pb[mt] = *(const bf16x8*)(QPs + rl * 64 + gr * 8);
            }
            #pragma unroll
            for (int dt = 0; dt < 4; dt++)
                #pragma unroll
                for (int mt = 0; mt < 2; mt++)
                    o[dt][mt] = __builtin_amdgcn_mfma_f32_16x16x32_bf16(
                        vb[ks][dt], pb[mt], o[dt][mt], 0, 0, 0);
        }

        // ---- rotate K double-buffer ----
        #pragma unroll
        for (int ks = 0; ks < 2; ks++)
            #pragma unroll
            for (int nt = 0; nt < 4; nt++)
                kb[ks][nt] = kbn[ks][nt];
    }

    // ---- epilogue: reduce l across quads (lanes l16, +16, +32, +48 share qrow) ----
    const int b = bh >> 4, h = bh & 15;
    #pragma unroll
    for (int mt = 0; mt < 2; mt++) {
        float lsum = l_part[mt];
        lsum += __shfl_xor(lsum, 16, 64);
        lsum += __shfl_xor(lsum, 32, 64);
        float inv = 1.0f / lsum;
        int srow = qb * QTILE + w * 32 + mt * 16 + l16;
        #pragma unroll
        for (int dt = 0; dt < 4; dt++) {
            bf16x4 ov;
            #pragma unroll
            for (int r = 0; r < 4; r++) ov[r] = (bf16_t)(o[dt][mt][r] * inv);
            *(bf16x4*)(attnb + ((size_t)(b * SEQ + srow)) * DIM + h * HD + dt * 16 + quad * 4) = ov;
        }
    }
}

extern "C" void kernel_launch(void* const* d_in, const int* in_sizes, int n_in,
                              void* d_out, int out_size, void* d_ws, size_t ws_size,
                              hipStream_t stream) {
    const float* x     = (const float*)d_in[0];
    const float* w_qkv = (const float*)d_in[1];
    const float* w_out = (const float*)d_in[2];
    float* out = (float*)d_out;

    bf16_t* xb    = (bf16_t*)d_ws;                          // 8192*1024
    bf16_t* wqkvT = xb    + (size_t)MROWS * DIM;            // 3072*1024
    bf16_t* woutT = wqkvT + (size_t)3 * DIM * DIM;          // 1024*1024
    bf16_t* qNb   = woutT + (size_t)DIM * DIM;              // 64*2048*64
    bf16_t* kNb   = qNb   + (size_t)BHTOT * SEQ * HD;
    bf16_t* vTb   = kNb   + (size_t)BHTOT * SEQ * HD;
    bf16_t* attnb = vTb   + (size_t)BHTOT * SEQ * HD;       // 8192*1024

    cast_x_kernel<<<MROWS * DIM / 1024, 256, 0, stream>>>(x, xb);
    transpose_cast_kernel<<<dim3(DIM / 32, 3 * DIM / 32), 256, 0, stream>>>(w_qkv, wqkvT, DIM, 3 * DIM);
    transpose_cast_kernel<<<dim3(DIM / 32, DIM / 32), 256, 0, stream>>>(w_out, woutT, DIM, DIM);
    gemm_qkv_kernel<<<dim3(MROWS / 128, 3 * DIM / 128), 256, 0, stream>>>(xb, wqkvT, qNb, kNb, vTb);
    attn_kernel<<<dim3(BHTOT, SEQ / QTILE), 256, 0, stream>>>(qNb, kNb, vTb, attnb);
    gemm_out_kernel<<<dim3(MROWS / 128, DIM / 128), 256, 0, stream>>>(attnb, woutT, out);
}

// Round 7
// 291.809 us; speedup vs baseline: 1.2417x; 1.1801x over previous
//
#include <hip/hip_runtime.h>
#include <float.h>

// B=4, S=2048, D=1024, H=16, hd=64. bf16 MFMA pipeline:
//   cast_x, transpose_cast(w_qkv), transpose_cast(w_out)
//   gemm_qkv (MFMA 128x128, C^T orientation for q/k packed stores)
//        -> qN (pre-scaled by 1/8*log2e), kN [bh][S][64], vT [bh][64][S]
//   attn (MFMA flash, K LDS double-buffer with one-iteration prefetch distance,
//         V global->VGPR, single barrier per K-tile, swizzled P^T)
//   gemm_out (MFMA 128x128, C^T orientation, float4 stores) -> out fp32

#define SEQ   2048
#define DIM   1024
#define NH    16
#define HD    64
#define MROWS 8192
#define BHTOT 64
#define QTILE 128

typedef __bf16 bf16_t;
typedef __bf16 bf16x4 __attribute__((ext_vector_type(4)));
typedef __bf16 bf16x8 __attribute__((ext_vector_type(8)));
typedef float  f32x4  __attribute__((ext_vector_type(4)));

typedef const __attribute__((address_space(1))) unsigned int* gas_ptr;
typedef __attribute__((address_space(3))) unsigned int* las_ptr;

__device__ __forceinline__ void gll16(const bf16_t* g, bf16_t* l) {
    __builtin_amdgcn_global_load_lds((gas_ptr)g, (las_ptr)l, 16, 0, 0);
}

// ---------------- cast kernels ----------------
__global__ __launch_bounds__(256) void cast_x_kernel(
    const float* __restrict__ x, bf16_t* __restrict__ xb)
{
    int i = (blockIdx.x * 256 + threadIdx.x) * 4;
    float4 v = *(const float4*)(x + i);
    bf16x4 o = { (bf16_t)v.x, (bf16_t)v.y, (bf16_t)v.z, (bf16_t)v.w };
    *(bf16x4*)(xb + i) = o;
}

// w [K][N] fp32 -> wT [N][K] bf16
__global__ __launch_bounds__(256) void transpose_cast_kernel(
    const float* __restrict__ w, bf16_t* __restrict__ wT, int K, int N)
{
    __shared__ float t[32][33];
    const int bk = blockIdx.x * 32, bn = blockIdx.y * 32;
    const int r = threadIdx.x >> 5, c = threadIdx.x & 31;
    #pragma unroll
    for (int i = 0; i < 4; i++)
        t[r + i * 8][c] = w[(size_t)(bk + r + i * 8) * N + bn + c];
    __syncthreads();
    #pragma unroll
    for (int i = 0; i < 4; i++)
        wT[(size_t)(bn + r + i * 8) * K + bk + c] = (bf16_t)t[c][r + i * 8];
}

// ---------------- GEMM qkv: 128x128 tile, BK=64, XOR-granule swizzle ----------------
// q/k blocks computed as C^T (operand swap) so the d-dimension lands in the
// accumulator's row direction -> packed bf16x4 stores into [bh][S][64].
__global__ __launch_bounds__(256) void gemm_qkv_kernel(
    const bf16_t* __restrict__ A,    // [8192][1024]
    const bf16_t* __restrict__ Bt,   // [3072][1024]
    bf16_t* __restrict__ qN, bf16_t* __restrict__ kN, bf16_t* __restrict__ vT)
{
    __shared__ bf16_t As[128 * 64];
    __shared__ bf16_t Bs[128 * 64];
    const int tid = threadIdx.x;
    const int lane = tid & 63, w = tid >> 6;
    const int quad = lane >> 4, l16 = lane & 15;
    const int wr = w >> 1, wc = w & 1;
    const int bm = blockIdx.x * 128, bn = blockIdx.y * 128;
    const int which = bn >> 10;   // 0=q, 1=k, 2=v (uniform per block)

    f32x4 acc[4][4] = {};

    for (int k0 = 0; k0 < DIM; k0 += 64) {
        __syncthreads();
        #pragma unroll
        for (int p = 0; p < 4; p++) {
            int flat = p * 256 + tid;
            int row = flat >> 3, g = flat & 7;
            int gs = g ^ (row & 7);
            gll16(A  + (size_t)(bm + row) * DIM + k0 + gs * 8, As + (size_t)(p * 256 + w * 64) * 8);
            gll16(Bt + (size_t)(bn + row) * DIM + k0 + gs * 8, Bs + (size_t)(p * 256 + w * 64) * 8);
        }
        __syncthreads();
        #pragma unroll
        for (int ks = 0; ks < 2; ks++) {
            bf16x8 af[4], bfv[4];
            #pragma unroll
            for (int mt = 0; mt < 4; mt++) {
                int row = wr * 64 + mt * 16 + l16;
                int g = (ks * 4 + quad) ^ (row & 7);
                af[mt] = *(const bf16x8*)(As + row * 64 + g * 8);
            }
            #pragma unroll
            for (int nt = 0; nt < 4; nt++) {
                int row = wc * 64 + nt * 16 + l16;
                int g = (ks * 4 + quad) ^ (row & 7);
                bfv[nt] = *(const bf16x8*)(Bs + row * 64 + g * 8);
            }
            if (which == 2) {
                #pragma unroll
                for (int mt = 0; mt < 4; mt++)
                    #pragma unroll
                    for (int nt = 0; nt < 4; nt++)
                        acc[mt][nt] = __builtin_amdgcn_mfma_f32_16x16x32_bf16(
                            af[mt], bfv[nt], acc[mt][nt], 0, 0, 0);
            } else {
                // C^T: rows = n (output col), cols = m
                #pragma unroll
                for (int nt = 0; nt < 4; nt++)
                    #pragma unroll
                    for (int mt = 0; mt < 4; mt++)
                        acc[nt][mt] = __builtin_amdgcn_mfma_f32_16x16x32_bf16(
                            bfv[nt], af[mt], acc[nt][mt], 0, 0, 0);
            }
        }
    }

    if (which == 2) {
        // vT[bh][d][S]: lane holds 4 consecutive s -> packed 8B stores
        #pragma unroll
        for (int mt = 0; mt < 4; mt++)
            #pragma unroll
            for (int nt = 0; nt < 4; nt++) {
                int row0 = bm + wr * 64 + mt * 16 + quad * 4;
                int b = row0 >> 11, s0 = row0 & 2047;
                int col = bn + wc * 64 + nt * 16 + l16;
                int nn = col & 1023, h = nn >> 6, d = nn & 63;
                int bh = b * NH + h;
                bf16x4 vv;
                #pragma unroll
                for (int r = 0; r < 4; r++) vv[r] = (bf16_t)acc[mt][nt][r];
                *(bf16x4*)(vT + ((size_t)bh * HD + d) * SEQ + s0) = vv;
            }
    } else {
        // C^T: lane holds 4 consecutive d for one s -> packed 8B stores
        const float qsc = (which == 0) ? 0.18033688011112042f : 1.0f; // (1/8)*log2(e)
        bf16_t* dst = (which == 0) ? qN : kN;
        #pragma unroll
        for (int mt = 0; mt < 4; mt++) {
            int m = bm + wr * 64 + mt * 16 + l16;
            int b = m >> 11, s = m & 2047;
            #pragma unroll
            for (int nt = 0; nt < 4; nt++) {
                int n = bn + wc * 64 + nt * 16 + quad * 4;
                int nn = n & 1023, h = nn >> 6, d0 = nn & 63;
                int bh = b * NH + h;
                bf16x4 pk;
                #pragma unroll
                for (int r = 0; r < 4; r++) pk[r] = (bf16_t)(acc[nt][mt][r] * qsc);
                *(bf16x4*)(dst + ((size_t)bh * SEQ + s) * HD + d0) = pk;
            }
        }
    }
}

// C^T orientation: packed float4 stores.
__global__ __launch_bounds__(256) void gemm_out_kernel(
    const bf16_t* __restrict__ A,    // attnb [8192][1024]
    const bf16_t* __restrict__ Bt,   // woutT [1024][1024]
    float* __restrict__ out)
{
    __shared__ bf16_t As[128 * 64];
    __shared__ bf16_t Bs[128 * 64];
    const int tid = threadIdx.x;
    const int lane = tid & 63, w = tid >> 6;
    const int quad = lane >> 4, l16 = lane & 15;
    const int wr = w >> 1, wc = w & 1;
    const int bm = blockIdx.x * 128, bn = blockIdx.y * 128;

    f32x4 acc[4][4] = {};   // acc[nt][mt]: C^T

    for (int k0 = 0; k0 < DIM; k0 += 64) {
        __syncthreads();
        #pragma unroll
        for (int p = 0; p < 4; p++) {
            int flat = p * 256 + tid;
            int row = flat >> 3, g = flat & 7;
            int gs = g ^ (row & 7);
            gll16(A  + (size_t)(bm + row) * DIM + k0 + gs * 8, As + (size_t)(p * 256 + w * 64) * 8);
            gll16(Bt + (size_t)(bn + row) * DIM + k0 + gs * 8, Bs + (size_t)(p * 256 + w * 64) * 8);
        }
        __syncthreads();
        #pragma unroll
        for (int ks = 0; ks < 2; ks++) {
            bf16x8 af[4], bfv[4];
            #pragma unroll
            for (int mt = 0; mt < 4; mt++) {
                int row = wr * 64 + mt * 16 + l16;
                int g = (ks * 4 + quad) ^ (row & 7);
                af[mt] = *(const bf16x8*)(As + row * 64 + g * 8);
            }
            #pragma unroll
            for (int nt = 0; nt < 4; nt++) {
                int row = wc * 64 + nt * 16 + l16;
                int g = (ks * 4 + quad) ^ (row & 7);
                bfv[nt] = *(const bf16x8*)(Bs + row * 64 + g * 8);
            }
            #pragma unroll
            for (int nt = 0; nt < 4; nt++)
                #pragma unroll
                for (int mt = 0; mt < 4; mt++)
                    acc[nt][mt] = __builtin_amdgcn_mfma_f32_16x16x32_bf16(
                        bfv[nt], af[mt], acc[nt][mt], 0, 0, 0);
        }
    }

    #pragma unroll
    for (int mt = 0; mt < 4; mt++) {
        int m = bm + wr * 64 + mt * 16 + l16;
        #pragma unroll
        for (int nt = 0; nt < 4; nt++) {
            int n0 = bn + wc * 64 + nt * 16 + quad * 4;
            float4 ov = { acc[nt][mt][0], acc[nt][mt][1], acc[nt][mt][2], acc[nt][mt][3] };
            *(float4*)(out + (size_t)m * DIM + n0) = ov;
        }
    }
}

// ---------------- MFMA flash attention: prefetched K LDS double-buffer ----------------
// grid (BHTOT, SEQ/QTILE), y->qb via magic square (per-CU balance).
// Wave w owns q-rows [w*32, w*32+32) (Q frags and P^T rows are wave-private ->
// only hazard is the K double buffer -> ONE barrier per K-tile).
// Pipeline: at iter top (just after barrier) issue gll16 K(kt+1) -> buf^1; it
// stays in flight for the whole compute phase and is drained exactly at the
// next loop-top barrier (cp.async-style, vmcnt never blocks mid-iter).
// V fragments global->VGPR, issued before the K gll16s so PV waits at vmcnt(2).
__device__ __constant__ int QB_TAB[16] = {0,11,7,12, 14,5,9,2, 13,6,10,1, 3,8,4,15};

#define ISSUEK(kt_, buf_) do {                                                   \
    _Pragma("unroll")                                                            \
    for (int p_ = 0; p_ < 2; p_++) {                                             \
        int flat_ = p_ * 256 + tid;                                              \
        int row_ = flat_ >> 3, g_ = flat_ & 7;                                   \
        int gs_ = g_ ^ (row_ & 7);                                               \
        gll16(kbase + (size_t)((kt_) * 64 + row_) * HD + gs_ * 8,                \
              &Ks2[buf_][0] + (size_t)(p_ * 256 + w * 64) * 8);                  \
    }                                                                            \
} while (0)

__global__ __launch_bounds__(256) void attn_kernel(
    const bf16_t* __restrict__ qN, const bf16_t* __restrict__ kN,
    const bf16_t* __restrict__ vT, bf16_t* __restrict__ attnb)
{
    __shared__ __align__(16) bf16_t QPs[QTILE * 64];   // 16 KB: Q tile, then P^T (same swizzle)
    __shared__ __align__(16) bf16_t Ks2[2][64 * 64];   // 16 KB: K double buffer

    const int bh = blockIdx.x;
    const int qb = QB_TAB[blockIdx.y];
    const int tid = threadIdx.x;
    const int lane = tid & 63, w = tid >> 6;
    const int quad = lane >> 4, l16 = lane & 15;

    const bf16_t* qbase = qN + (size_t)bh * SEQ * HD;
    const bf16_t* kbase = kN + (size_t)bh * SEQ * HD;
    const bf16_t* vbase = vT + (size_t)bh * HD * SEQ;

    // stage Q tile (128x64, XOR-granule swizzle)
    #pragma unroll
    for (int p = 0; p < 4; p++) {
        int flat = p * 256 + tid;
        int row = flat >> 3, g = flat & 7;
        int gs = g ^ (row & 7);
        gll16(qbase + (size_t)(qb * QTILE + row) * HD + gs * 8,
              QPs + (size_t)(p * 256 + w * 64) * 8);
    }
    __syncthreads();                 // Q resident

    ISSUEK(0, 0);                    // K tile 0 in flight; drained at first loop barrier

    bf16x8 qa[2][2];                 // B-operand fragments (wave-private rows)
    #pragma unroll
    for (int mt = 0; mt < 2; mt++)
        #pragma unroll
        for (int ks = 0; ks < 2; ks++) {
            int row = w * 32 + mt * 16 + l16;
            int g = (ks * 4 + quad) ^ (row & 7);
            qa[mt][ks] = *(const bf16x8*)(QPs + row * 64 + g * 8);
        }

    f32x4 o[4][2] = {};        // O^T: rows d = dt*16+quad*4+r, col qrow = l16 (mt block)
    float l_part[2] = {};

    const int ktmax = 2 * qb + 1;
    const int wave_row_max = qb * QTILE + w * 32 + 31;

    for (int kt = 0; kt <= ktmax; kt++) {
        __syncthreads();             // K[kt&1] ready; opposite-parity buffer free

        const bool active = (kt * 64 <= wave_row_max);

        // ---- V fragments for this kt (issued before K gll16: PV waits vmcnt(2)) ----
        bf16x8 vb[2][4];
        if (active) {
            #pragma unroll
            for (int ks = 0; ks < 2; ks++)
                #pragma unroll
                for (int dt = 0; dt < 4; dt++)
                    vb[ks][dt] = *(const bf16x8*)(
                        vbase + (size_t)(dt * 16 + l16) * SEQ + kt * 64 + ks * 32 + quad * 8);
        }

        // ---- prefetch next K tile (in flight until next loop-top barrier) ----
        if (kt < ktmax) ISSUEK(kt + 1, (kt + 1) & 1);

        if (!active) continue;       // fully-masked wave: barrier + issue only

        const bf16_t* Kb = &Ks2[kt & 1][0];

        // ---- S^T = K Q^T : s[nt][mt], key = kt*64+nt*16+quad*4+r, qrow col = l16 ----
        f32x4 s[4][2] = {};
        #pragma unroll
        for (int ks = 0; ks < 2; ks++) {
            bf16x8 kb[4];
            #pragma unroll
            for (int nt = 0; nt < 4; nt++) {
                int row = nt * 16 + l16;
                int g = (ks * 4 + quad) ^ (row & 7);
                kb[nt] = *(const bf16x8*)(Kb + row * 64 + g * 8);
            }
            #pragma unroll
            for (int nt = 0; nt < 4; nt++)
                #pragma unroll
                for (int mt = 0; mt < 2; mt++)
                    s[nt][mt] = __builtin_amdgcn_mfma_f32_16x16x32_bf16(
                        kb[nt], qa[mt][ks], s[nt][mt], 0, 0, 0);
        }

        // ---- p = exp2(s) (Q pre-scaled), accumulate l, swizzled packed P^T store ----
        const bool maskit = (kt >= 2 * qb);
        #pragma unroll
        for (int mt = 0; mt < 2; mt++) {
            const int rl = w * 32 + mt * 16 + l16;          // qrow local
            const int qrow = qb * QTILE + rl;
            #pragma unroll
            for (int nt = 0; nt < 4; nt++) {
                bf16x4 pk;
                #pragma unroll
                for (int r = 0; r < 4; r++) {
                    float pv;
                    if (maskit) {
                        int key = kt * 64 + nt * 16 + quad * 4 + r;
                        pv = (key <= qrow) ? __builtin_amdgcn_exp2f(s[nt][mt][r]) : 0.0f;
                    } else {
                        pv = __builtin_amdgcn_exp2f(s[nt][mt][r]);
                    }
                    l_part[mt] += pv;
                    pk[r] = (bf16_t)pv;
                }
                // key granule = nt*2 + (quad>>1); within-granule offset = (quad&1)*4
                int gw = (nt * 2 + (quad >> 1)) ^ (rl & 7);
                *(bf16x4*)(QPs + rl * 64 + gw * 8 + (quad & 1) * 4) = pk;
            }
        }

        // ---- O^T += V^T P^T ----
        #pragma unroll
        for (int ks = 0; ks < 2; ks++) {
            bf16x8 pb[2];
            #pragma unroll
            for (int mt = 0; mt < 2; mt++) {
                int rl = w * 32 + mt * 16 + l16;
                int gr = (ks * 4 + quad) ^ (rl & 7);
                pb[mt] = *(const bf16x8*)(QPs + rl * 64 + gr * 8);
            }
            #pragma unroll
            for (int dt = 0; dt < 4; dt++)
                #pragma unroll
                for (int mt = 0; mt < 2; mt++)
                    o[dt][mt] = __builtin_amdgcn_mfma_f32_16x16x32_bf16(
                        vb[ks][dt], pb[mt], o[dt][mt], 0, 0, 0);
        }
    }

    // ---- epilogue: reduce l across quads (lanes l16, +16, +32, +48 share qrow) ----
    const int b = bh >> 4, h = bh & 15;
    #pragma unroll
    for (int mt = 0; mt < 2; mt++) {
        float lsum = l_part[mt];
        lsum += __shfl_xor(lsum, 16, 64);
        lsum += __shfl_xor(lsum, 32, 64);
        float inv = 1.0f / lsum;
        int srow = qb * QTILE + w * 32 + mt * 16 + l16;
        #pragma unroll
        for (int dt = 0; dt < 4; dt++) {
            bf16x4 ov;
            #pragma unroll
            for (int r = 0; r < 4; r++) ov[r] = (bf16_t)(o[dt][mt][r] * inv);
            *(bf16x4*)(attnb + ((size_t)(b * SEQ + srow)) * DIM + h * HD + dt * 16 + quad * 4) = ov;
        }
    }
}

extern "C" void kernel_launch(void* const* d_in, const int* in_sizes, int n_in,
                              void* d_out, int out_size, void* d_ws, size_t ws_size,
                              hipStream_t stream) {
    const float* x     = (const float*)d_in[0];
    const float* w_qkv = (const float*)d_in[1];
    const float* w_out = (const float*)d_in[2];
    float* out = (float*)d_out;

    bf16_t* xb    = (bf16_t*)d_ws;                          // 8192*1024
    bf16_t* wqkvT = xb    + (size_t)MROWS * DIM;            // 3072*1024
    bf16_t* woutT = wqkvT + (size_t)3 * DIM * DIM;          // 1024*1024
    bf16_t* qNb   = woutT + (size_t)DIM * DIM;              // 64*2048*64
    bf16_t* kNb   = qNb   + (size_t)BHTOT * SEQ * HD;
    bf16_t* vTb   = kNb   + (size_t)BHTOT * SEQ * HD;
    bf16_t* attnb = vTb   + (size_t)BHTOT * SEQ * HD;       // 8192*1024

    cast_x_kernel<<<MROWS * DIM / 1024, 256, 0, stream>>>(x, xb);
    transpose_cast_kernel<<<dim3(DIM / 32, 3 * DIM / 32), 256, 0, stream>>>(w_qkv, wqkvT, DIM, 3 * DIM);
    transpose_cast_kernel<<<dim3(DIM / 32, DIM / 32), 256, 0, stream>>>(w_out, woutT, DIM, DIM);
    gemm_qkv_kernel<<<dim3(MROWS / 128, 3 * DIM / 128), 256, 0, stream>>>(xb, wqkvT, qNb, kNb, vTb);
    attn_kernel<<<dim3(BHTOT, SEQ / QTILE), 256, 0, stream>>>(qNb, kNb, vTb, attnb);
    gemm_out_kernel<<<dim3(MROWS / 128, DIM / 128), 256, 0, stream>>>(attnb, woutT, out);
}